// Round 1
// baseline (210.254 us; speedup 1.0000x reference)
//
#include <hip/hip_runtime.h>

typedef __bf16 bf16x8 __attribute__((ext_vector_type(8)));
typedef float f32x4 __attribute__((ext_vector_type(4)));

#define S 512
#define CH 16

__device__ __forceinline__ float swishf(float z) {
    float e = __expf(-z);
    return z * __builtin_amdgcn_rcpf(1.0f + e);
}

// ws layout: [0,17408) : 17 B-fragments x 64 lanes x 8 bf16
//   frag 0..11 : W1 (pad K 80->96), frag = u*3+t  (u: n-tile of 16, t: k-step of 32)
//   frag 12..15: W2, frag = 12 + u*2 + t
//   frag 16    : W3
// [17408,17856): fp32 biases b1[64] b2[32] b3[16]
__global__ void prep_weights(const float* __restrict__ W1, const float* __restrict__ b1,
                             const float* __restrict__ W2, const float* __restrict__ b2,
                             const float* __restrict__ W3, const float* __restrict__ b3,
                             __bf16* __restrict__ wsf, float* __restrict__ wsb)
{
    int idx = blockIdx.x * 256 + threadIdx.x;
    if (idx < 17 * 512) {
        int frag = idx >> 9;
        int lane = (idx >> 3) & 63;
        int j = idx & 7;
        int lr = lane & 15, lg = lane >> 4;
        float v = 0.0f;
        if (frag < 12) {
            int u = frag / 3, tt = frag - u * 3;
            int k = tt * 32 + lg * 8 + j;
            if (k < 80) v = W1[k * 64 + u * 16 + lr];
        } else if (frag < 16) {
            int f2 = frag - 12;
            int u = f2 >> 1, tt = f2 & 1;
            int k = tt * 32 + lg * 8 + j;
            v = W2[k * 32 + u * 16 + lr];
        } else {
            int k = lg * 8 + j;
            v = W3[k * 16 + lr];
        }
        wsf[idx] = (__bf16)v;
    }
    if (blockIdx.x == 0) {
        int t = threadIdx.x;
        if (t < 64) wsb[t] = b1[t];
        else if (t < 96) wsb[t] = b2[t - 64];
        else if (t < 112) wsb[t] = b3[t - 96];
    }
}

__global__ __launch_bounds__(256) void nca_fused(
    const float* __restrict__ x, const float* __restrict__ noise,
    const __bf16* __restrict__ wsf, const float* __restrict__ wsb,
    float* __restrict__ out)
{
    __shared__ float xs[3 * 66 * 20];          // [row][col][ch pad 20]
    __shared__ unsigned int yb[64 * 52];       // y bf16 pairs, row stride 52 dw (=104 bf16, K pad 96)
    __shared__ __bf16 h1s[64 * 72];            // stride 72
    __shared__ __bf16 h2s[64 * 40];            // stride 40

    const int tid = threadIdx.x;
    const int strip = blockIdx.x;
    const int w0 = (strip & 7) * 64;
    const int hrow = (strip >> 3) & (S - 1);
    const int bb = strip >> 12;

    const int lane = tid & 63;
    const int wv = tid >> 6;
    const int lr = lane & 15, lg = lane >> 4;

    // ---- weight fragments (L1-hot, perfectly coalesced) ----
    const bf16x8* __restrict__ wfp = reinterpret_cast<const bf16x8*>(wsf);
    bf16x8 w1f[4][3], w2f[2][2], w3f;
#pragma unroll
    for (int u = 0; u < 4; ++u)
#pragma unroll
        for (int t = 0; t < 3; ++t) w1f[u][t] = wfp[(u * 3 + t) * 64 + lane];
#pragma unroll
    for (int u = 0; u < 2; ++u)
#pragma unroll
        for (int t = 0; t < 2; ++t) w2f[u][t] = wfp[(12 + u * 2 + t) * 64 + lane];
    w3f = wfp[16 * 64 + lane];
    float b1v[4], b2v[2], b3v;
#pragma unroll
    for (int u = 0; u < 4; ++u) b1v[u] = wsb[u * 16 + lr];
#pragma unroll
    for (int u = 0; u < 2; ++u) b2v[u] = wsb[64 + u * 16 + lr];
    b3v = wsb[96 + lr];

    // ---- stage x: rows hrow-1..hrow+1, cols w0-1..w0+64, 16 ch (zero pad OOB) ----
    for (int i = tid; i < 792; i += 256) {           // 3 rows * 264 float4
        int r = i / 264;
        int q = i - r * 264;
        int w = w0 - 1 + (q >> 2);
        int c4 = (q & 3) << 2;
        int gr = hrow - 1 + r;
        float4 v = make_float4(0.f, 0.f, 0.f, 0.f);
        if ((unsigned)gr < (unsigned)S && (unsigned)w < (unsigned)S)
            v = *reinterpret_cast<const float4*>(x + ((bb * S + gr) * S + w) * CH + c4);
        *reinterpret_cast<float4*>(&xs[(r * 66 + (w - w0 + 1)) * 20 + c4]) = v;
    }
    __syncthreads();

    // ---- perceive: wave wv -> features [wv*20, wv*20+20) for all 64 pixels ----
    {
        const int p = lane;        // pixel in strip
        const int g = wv;          // channel group (4 channels)
        float A[3][3][4];
#pragma unroll
        for (int r = 0; r < 3; ++r)
#pragma unroll
            for (int d = 0; d < 3; ++d) {
                float4 t4 = *reinterpret_cast<const float4*>(&xs[(r * 66 + p + d) * 20 + g * 4]);
                A[r][d][0] = t4.x; A[r][d][1] = t4.y; A[r][d][2] = t4.z; A[r][d][3] = t4.w;
            }
        unsigned short fs[20];
#pragma unroll
        for (int cc = 0; cc < 4; ++cc) {
            float cw0 = A[0][0][cc] + 2.f * A[1][0][cc] + A[2][0][cc];
            float cw1 = A[0][1][cc] + 2.f * A[1][1][cc] + A[2][1][cc];
            float cw2 = A[0][2][cc] + 2.f * A[1][2][cc] + A[2][2][cc];
            float rw0 = A[0][0][cc] + 2.f * A[0][1][cc] + A[0][2][cc];
            float rw2 = A[2][0][cc] + 2.f * A[2][1][cc] + A[2][2][cc];
            float ctr = A[1][1][cc];
            float fI  = ctr;
            float fdx = (cw2 - cw0) * 0.125f;
            float fdy = (rw2 - rw0) * 0.125f;
            float flp = 0.25f * (cw0 + 2.f * cw1 + cw2) - 4.f * ctr;
            float fav = ((cw0 + cw1 + cw2) - (A[1][0][cc] + A[1][1][cc] + A[1][2][cc])) * (1.f / 9.f);
            fs[cc * 5 + 0] = __builtin_bit_cast(unsigned short, (__bf16)fI);
            fs[cc * 5 + 1] = __builtin_bit_cast(unsigned short, (__bf16)fdx);
            fs[cc * 5 + 2] = __builtin_bit_cast(unsigned short, (__bf16)fdy);
            fs[cc * 5 + 3] = __builtin_bit_cast(unsigned short, (__bf16)flp);
            fs[cc * 5 + 4] = __builtin_bit_cast(unsigned short, (__bf16)fav);
        }
        unsigned int* dst = &yb[p * 52 + g * 10];
#pragma unroll
        for (int m = 0; m < 10; ++m)
            dst[m] = (unsigned int)fs[2 * m] | ((unsigned int)fs[2 * m + 1] << 16);
        if (g == 3) {                               // zero K-pad 80..95 (LDS is uninitialized!)
#pragma unroll
            for (int m = 0; m < 8; ++m) yb[p * 52 + 40 + m] = 0u;
        }
    }
    __syncthreads();

    // ---- GEMM1: [16px x 96] x [96 x 64] per wave ----
    const int mt = wv;
    bf16x8 a1[3];
#pragma unroll
    for (int t = 0; t < 3; ++t)
        a1[t] = *reinterpret_cast<const bf16x8*>(&yb[(mt * 16 + lr) * 52 + t * 16 + lg * 4]);
#pragma unroll
    for (int u = 0; u < 4; ++u) {
        f32x4 acc = {0.f, 0.f, 0.f, 0.f};
#pragma unroll
        for (int t = 0; t < 3; ++t)
            acc = __builtin_amdgcn_mfma_f32_16x16x32_bf16(a1[t], w1f[u][t], acc, 0, 0, 0);
#pragma unroll
        for (int r = 0; r < 4; ++r) {
            float h = swishf(acc[r] + b1v[u]);      // D: row=(lg*4+r), col=lr (m89-verified)
            h1s[(mt * 16 + lg * 4 + r) * 72 + u * 16 + lr] = (__bf16)h;
        }
    }
    __syncthreads();

    // ---- GEMM2: [16 x 64] x [64 x 32] ----
    bf16x8 a2[2];
#pragma unroll
    for (int t = 0; t < 2; ++t)
        a2[t] = *reinterpret_cast<const bf16x8*>(&h1s[(mt * 16 + lr) * 72 + t * 32 + lg * 8]);
#pragma unroll
    for (int u = 0; u < 2; ++u) {
        f32x4 acc = {0.f, 0.f, 0.f, 0.f};
#pragma unroll
        for (int t = 0; t < 2; ++t)
            acc = __builtin_amdgcn_mfma_f32_16x16x32_bf16(a2[t], w2f[u][t], acc, 0, 0, 0);
#pragma unroll
        for (int r = 0; r < 4; ++r) {
            float h = swishf(acc[r] + b2v[u]);
            h2s[(mt * 16 + lg * 4 + r) * 40 + u * 16 + lr] = (__bf16)h;
        }
    }
    __syncthreads();

    // ---- GEMM3: [16 x 32] x [32 x 16] + masked residual ----
    bf16x8 a3 = *reinterpret_cast<const bf16x8*>(&h2s[(mt * 16 + lr) * 40 + lg * 8]);
    f32x4 acc = {0.f, 0.f, 0.f, 0.f};
    acc = __builtin_amdgcn_mfma_f32_16x16x32_bf16(a3, w3f, acc, 0, 0, 0);
#pragma unroll
    for (int r = 0; r < 4; ++r) {
        int prow = mt * 16 + lg * 4 + r;            // pixel in strip
        int pix = (bb * S + hrow) * S + (w0 + prow);
        float cx = xs[(66 + prow + 1) * 20 + lr];   // center x from staged tile
        float m = (noise[pix] <= 0.5f) ? 1.f : 0.f;
        out[pix * CH + lr] = cx + (acc[r] + b3v) * m;
    }
}

extern "C" void kernel_launch(void* const* d_in, const int* in_sizes, int n_in,
                              void* d_out, int out_size, void* d_ws, size_t ws_size,
                              hipStream_t stream)
{
    const float* x     = (const float*)d_in[0];
    const float* noise = (const float*)d_in[1];
    const float* W1    = (const float*)d_in[2];
    const float* b1    = (const float*)d_in[3];
    const float* W2    = (const float*)d_in[4];
    const float* b2    = (const float*)d_in[5];
    const float* W3    = (const float*)d_in[6];
    const float* b3    = (const float*)d_in[7];
    __bf16* wsf = (__bf16*)d_ws;
    float*  wsb = (float*)((char*)d_ws + 17408);
    float*  out = (float*)d_out;

    hipLaunchKernelGGL(prep_weights, dim3(34), dim3(256), 0, stream,
                       W1, b1, W2, b2, W3, b3, wsf, wsb);
    hipLaunchKernelGGL(nca_fused, dim3(4 * 512 * 8), dim3(256), 0, stream,
                       x, noise, wsf, wsb, out);
}

// Round 2
// 178.124 us; speedup vs baseline: 1.1804x; 1.1804x over previous
//
#include <hip/hip_runtime.h>

typedef __bf16 bf16x8 __attribute__((ext_vector_type(8)));
typedef float f32x4 __attribute__((ext_vector_type(4)));
typedef float f32x16 __attribute__((ext_vector_type(16)));
typedef short short8 __attribute__((ext_vector_type(8)));

#define S 512
#define CH 16

#define ELT(v, c) ((c)==0 ? (v).x : (c)==1 ? (v).y : (c)==2 ? (v).z : (v).w)

__device__ __forceinline__ float swishf(float z) {
    return z * __builtin_amdgcn_rcpf(1.0f + __expf(-z));
}

// ws shorts layout:
// [0,5120)    : W1 B-frags for 32x32x16 GEMM1: fi = n*5+s, element [fi*512 + lane*8 + j]
//               k-map: m=s*8+j, cc=m/5, f=m%5, ch=blk*8+cc (blk=lane>>5), W1row=ch*5+f
// [5120,7168) : W2 B-frags 16x16x32: fi = u2*2+t, k = t*32+(lane>>4)*8+j
// [7168,7680) : W3 B-frag 16x16x32: k = (lane>>4)*8+j
// byte 15360  : f32 biases b1[64] b2[32] b3[16]
__global__ void prep_weights(const float* __restrict__ W1, const float* __restrict__ b1,
                             const float* __restrict__ W2, const float* __restrict__ b2,
                             const float* __restrict__ W3, const float* __restrict__ b3,
                             short* __restrict__ wsf, float* __restrict__ wsb)
{
    int idx = blockIdx.x * 256 + threadIdx.x;
    if (idx < 7680) {
        float v;
        if (idx < 5120) {
            int fi = idx >> 9, rem = idx & 511;
            int lane = rem >> 3, j = rem & 7;
            int n = fi / 5, s = fi - n * 5;
            int blk = lane >> 5, colw = lane & 31;
            int m = s * 8 + j, cc = m / 5, f = m - cc * 5;
            int row = (blk * 8 + cc) * 5 + f;
            v = W1[row * 64 + n * 32 + colw];
        } else if (idx < 7168) {
            int i2 = idx - 5120;
            int fi = i2 >> 9, rem = i2 & 511;
            int lane = rem >> 3, j = rem & 7;
            int u2 = fi >> 1, t = fi & 1;
            int k = t * 32 + (lane >> 4) * 8 + j;
            v = W2[k * 32 + u2 * 16 + (lane & 15)];
        } else {
            int i3 = idx - 7168;
            int lane = i3 >> 3, j = i3 & 7;
            int k = (lane >> 4) * 8 + j;
            v = W3[k * 16 + (lane & 15)];
        }
        __bf16 b = (__bf16)v;
        wsf[idx] = __builtin_bit_cast(short, b);
    }
    if (blockIdx.x == 0) {
        int t = threadIdx.x;
        if (t < 64) wsb[t] = b1[t];
        else if (t < 96) wsb[t] = b2[t - 64];
        else if (t < 112) wsb[t] = b3[t - 96];
    }
}

__global__ __launch_bounds__(256, 4) void nca_fused(
    const float* __restrict__ x, const float* __restrict__ noise,
    const short* __restrict__ wsf, const float* __restrict__ wsb,
    float* __restrict__ out)
{
    __shared__ short wlds[7680];               // 15360 B weight frags
    __shared__ __bf16 h1s[4][32][72];          // per-wave, stride 72 (144B, conflict-spread)
    __shared__ __bf16 h2s[4][16][40];          // per-wave, stride 40 (80B)

    const int tid = threadIdx.x;
    {   // one-time weight stage (the ONLY barrier in the kernel)
        const int4* src = reinterpret_cast<const int4*>(wsf);
        int4* dst = reinterpret_cast<int4*>(wlds);
        for (int i = tid; i < 960; i += 256) dst[i] = src[i];
    }
    __syncthreads();

    const int bid = blockIdx.x;
    const int st = bid & 7;                    // 8 strips of 64 cols
    const int rg = (bid >> 3) & 127;           // 128 row groups of 4
    const int bb = bid >> 10;                  // batch
    const int wv = tid >> 6;
    const int lane = tid & 63;
    const int col = lane & 31, hi = lane >> 5; // 32x32 ids
    const int lr = lane & 15, lg = lane >> 4;  // 16x16 ids
    const int row = rg * 4 + wv;               // each wave owns one image row

    float b1v[2], b2v[2], b3v;
    b1v[0] = wsb[col];        b1v[1] = wsb[32 + col];
    b2v[0] = wsb[64 + lr];    b2v[1] = wsb[80 + lr];
    b3v = wsb[96 + lr];

    const bool rv0 = row > 0, rv2 = row < S - 1;
    const float* xb = x + (size_t)bb * S * S * CH;
    const short8* wf = reinterpret_cast<const short8*>(wlds);

#pragma unroll
    for (int mt = 0; mt < 2; ++mt) {
        const int px0 = st * 64 + mt * 32;
        const bool colInt = (px0 != 0) && (px0 != 480);
        const int p = col;                     // pixel within 32-px tile

        short8 af[5];                          // A-frags, filled directly by perceive
#pragma unroll
        for (int qi = 0; qi < 2; ++qi) {
            const int q = hi * 2 + qi;         // channel quad (ch q*4..q*4+3)
            float4 A[3][3];
#pragma unroll
            for (int rr = 0; rr < 3; ++rr) {
                bool rok = (rr == 0) ? rv0 : (rr == 2 ? rv2 : true);
                if (rok) {
                    const float* rp = xb + (size_t)(row - 1 + rr) * S * CH + q * 4;
                    if (colInt) {
                        const float* bp = rp + (px0 + p - 1) * CH;
                        A[rr][0] = *reinterpret_cast<const float4*>(bp);
                        A[rr][1] = *reinterpret_cast<const float4*>(bp + CH);
                        A[rr][2] = *reinterpret_cast<const float4*>(bp + 2 * CH);
                    } else {
#pragma unroll
                        for (int d = 0; d < 3; ++d) {
                            int c = px0 + p - 1 + d;
                            int cl = min(max(c, 0), S - 1);
                            float4 v = *reinterpret_cast<const float4*>(rp + cl * CH);
                            if ((unsigned)c >= (unsigned)S) v = make_float4(0.f, 0.f, 0.f, 0.f);
                            A[rr][d] = v;
                        }
                    }
                } else {
                    A[rr][0] = make_float4(0.f, 0.f, 0.f, 0.f);
                    A[rr][1] = A[rr][0]; A[rr][2] = A[rr][0];
                }
            }
#pragma unroll
            for (int cc = 0; cc < 4; ++cc) {
                float a00 = ELT(A[0][0], cc), a01 = ELT(A[0][1], cc), a02 = ELT(A[0][2], cc);
                float a10 = ELT(A[1][0], cc), a11 = ELT(A[1][1], cc), a12 = ELT(A[1][2], cc);
                float a20 = ELT(A[2][0], cc), a21 = ELT(A[2][1], cc), a22 = ELT(A[2][2], cc);
                float cw0 = a00 + 2.f * a10 + a20;
                float cw1 = a01 + 2.f * a11 + a21;
                float cw2 = a02 + 2.f * a12 + a22;
                float rw0 = a00 + 2.f * a01 + a02;
                float rw2 = a20 + 2.f * a21 + a22;
                float fI  = a11;
                float fdx = (cw2 - cw0) * 0.125f;
                float fdy = (rw2 - rw0) * 0.125f;
                float flp = 0.25f * (cw0 + 2.f * cw1 + cw2) - 4.f * a11;
                float fav = ((cw0 + cw1 + cw2) - (a10 + a11 + a12)) * (1.f / 9.f);
                const int mb = (qi * 4 + cc) * 5;
                af[(mb + 0) >> 3][(mb + 0) & 7] = __builtin_bit_cast(short, (__bf16)fI);
                af[(mb + 1) >> 3][(mb + 1) & 7] = __builtin_bit_cast(short, (__bf16)fdx);
                af[(mb + 2) >> 3][(mb + 2) & 7] = __builtin_bit_cast(short, (__bf16)fdy);
                af[(mb + 3) >> 3][(mb + 3) & 7] = __builtin_bit_cast(short, (__bf16)flp);
                af[(mb + 4) >> 3][(mb + 4) & 7] = __builtin_bit_cast(short, (__bf16)fav);
            }
        }

        // ---- GEMM1: [32px x 80] x [80 x 64], 32x32x16, A direct from regs ----
#pragma unroll
        for (int n = 0; n < 2; ++n) {
            f32x16 acc = {};
#pragma unroll
            for (int s = 0; s < 5; ++s) {
                bf16x8 a = __builtin_bit_cast(bf16x8, af[s]);
                bf16x8 b = __builtin_bit_cast(bf16x8, wf[(n * 5 + s) * 64 + lane]);
                acc = __builtin_amdgcn_mfma_f32_32x32x16_bf16(a, b, acc, 0, 0, 0);
            }
#pragma unroll
            for (int r = 0; r < 16; ++r) {     // D: col=l&31(feat), row=(r&3)+8*(r>>2)+4*hi(px)
                int p2 = (r & 3) + 8 * (r >> 2) + 4 * hi;
                h1s[wv][p2][n * 32 + col] = (__bf16)swishf(acc[r] + b1v[n]);
            }
        }

        // ---- GEMM2+GEMM3 per 16-px subtile (R1-verified 16x16x32 path) ----
#pragma unroll
        for (int sub = 0; sub < 2; ++sub) {
            bf16x8 a2[2];
#pragma unroll
            for (int t = 0; t < 2; ++t)
                a2[t] = *reinterpret_cast<const bf16x8*>(&h1s[wv][sub * 16 + lr][t * 32 + lg * 8]);
#pragma unroll
            for (int u2 = 0; u2 < 2; ++u2) {
                f32x4 acc2 = {};
#pragma unroll
                for (int t = 0; t < 2; ++t) {
                    bf16x8 b = __builtin_bit_cast(bf16x8, wf[640 + (u2 * 2 + t) * 64 + lane]);
                    acc2 = __builtin_amdgcn_mfma_f32_16x16x32_bf16(a2[t], b, acc2, 0, 0, 0);
                }
#pragma unroll
                for (int r = 0; r < 4; ++r)
                    h2s[wv][lg * 4 + r][u2 * 16 + lr] = (__bf16)swishf(acc2[r] + b2v[u2]);
            }
            bf16x8 a3 = *reinterpret_cast<const bf16x8*>(&h2s[wv][lr][lg * 8]);
            bf16x8 b3f = __builtin_bit_cast(bf16x8, wf[896 + lane]);
            f32x4 acc3 = {};
            acc3 = __builtin_amdgcn_mfma_f32_16x16x32_bf16(a3, b3f, acc3, 0, 0, 0);
#pragma unroll
            for (int r = 0; r < 4; ++r) {
                int pxg = px0 + sub * 16 + lg * 4 + r;
                size_t pix = (size_t)(bb * S + row) * S + pxg;
                float cx = x[pix * CH + lr];
                float msk = (noise[pix] <= 0.5f) ? 1.f : 0.f;
                out[pix * CH + lr] = cx + (acc3[r] + b3v) * msk;
            }
        }
    }
}

extern "C" void kernel_launch(void* const* d_in, const int* in_sizes, int n_in,
                              void* d_out, int out_size, void* d_ws, size_t ws_size,
                              hipStream_t stream)
{
    const float* x     = (const float*)d_in[0];
    const float* noise = (const float*)d_in[1];
    const float* W1    = (const float*)d_in[2];
    const float* b1    = (const float*)d_in[3];
    const float* W2    = (const float*)d_in[4];
    const float* b2    = (const float*)d_in[5];
    const float* W3    = (const float*)d_in[6];
    const float* b3    = (const float*)d_in[7];
    short* wsf = (short*)d_ws;
    float* wsb = (float*)((char*)d_ws + 15360);
    float* out = (float*)d_out;

    hipLaunchKernelGGL(prep_weights, dim3(30), dim3(256), 0, stream,
                       W1, b1, W2, b2, W3, b3, wsf, wsb);
    hipLaunchKernelGGL(nca_fused, dim3(4 * 128 * 8), dim3(256), 0, stream,
                       x, noise, wsf, wsb, out);
}

// Round 3
// 177.746 us; speedup vs baseline: 1.1829x; 1.0021x over previous
//
#include <hip/hip_runtime.h>

typedef __bf16 bf16x8 __attribute__((ext_vector_type(8)));
typedef float f32x4 __attribute__((ext_vector_type(4)));
typedef float f32x16 __attribute__((ext_vector_type(16)));
typedef short short8 __attribute__((ext_vector_type(8)));

#define S 512
#define CH 16

#define ELT(v, c) ((c)==0 ? (v).x : (c)==1 ? (v).y : (c)==2 ? (v).z : (v).w)

__device__ __forceinline__ float swishf(float z) {
    return z * __builtin_amdgcn_rcpf(1.0f + __expf(-z));
}

// All GEMMs computed transposed: D = W^T * data, so weights are the A-operand.
// 32x32x16 frag maps (R2-verified): A[row=l&31][k=(l>>5)*8+j], B[k=(l>>5)*8+j][col=l&31],
// D reg r: [row=(r&3)+8*(r>>2)+4*(l>>5)][col=l&31].
// K-permutations (applied to weight rows so data frags are lane-local):
//   GEMM1 (K=80, 5 steps): k-slot(s,hi,j) -> in-feature hi*40 + s*8 + j
//   GEMM2 (K=64, 4 steps): k-slot(t,hi,j) -> h1-feat (t>>1)*32 + 4*hi + (t&1)*16 + (j&3)+8*(j>>2)
//   GEMM3 (K=32, 2 steps): k-slot(t,hi,j) -> h2-feat 4*hi + t*16 + (j&3)+8*(j>>2)
// ws: shorts[0,8192): 16 A-frags x 64 lanes x 8bf16 (A1:0-9 [n*5+s], A2:10-13, A3:14-15)
//     byte 16384: f32 biases b1[64] b2[32] b3[16]
__global__ void prep_weights(const float* __restrict__ W1, const float* __restrict__ b1,
                             const float* __restrict__ W2, const float* __restrict__ b2,
                             const float* __restrict__ W3, const float* __restrict__ b3,
                             short* __restrict__ wsf, float* __restrict__ wsb)
{
    int idx = blockIdx.x * 256 + threadIdx.x;
    if (idx < 8192) {
        int fi = idx >> 9, rem = idx & 511;
        int lane = rem >> 3, j = rem & 7;
        int col = lane & 31, hi = lane >> 5;
        int jp = (j & 3) + 8 * (j >> 2);
        float v;
        if (fi < 10) {
            int n = fi / 5, s = fi - n * 5;
            int rowW = hi * 40 + s * 8 + j;             // pi1
            v = W1[rowW * 64 + n * 32 + col];
        } else if (fi < 14) {
            int t = fi - 10;
            int rowW = (t >> 1) * 32 + 4 * hi + (t & 1) * 16 + jp;   // pi2
            v = W2[rowW * 32 + col];
        } else {
            int t = fi - 14;
            int rowW = 4 * hi + t * 16 + jp;            // pi3
            v = (col < 16) ? W3[rowW * 16 + col] : 0.0f; // pad M 16->32
        }
        __bf16 b = (__bf16)v;
        wsf[idx] = __builtin_bit_cast(short, b);
    }
    if (blockIdx.x == 0) {
        int t = threadIdx.x;
        if (t < 64) wsb[t] = b1[t];
        else if (t < 96) wsb[t] = b2[t - 64];
        else if (t < 112) wsb[t] = b3[t - 96];
    }
}

__global__ __launch_bounds__(256, 5) void nca_fused(
    const float* __restrict__ x, const float* __restrict__ noise,
    const short* __restrict__ wsf, const float* __restrict__ wsb,
    float* __restrict__ out)
{
    __shared__ short wlds[8192];                        // 16 KB, weights only
    {
        const int4* src = reinterpret_cast<const int4*>(wsf);
        int4* dst = reinterpret_cast<int4*>(wlds);
        for (int i = threadIdx.x; i < 1024; i += 256) dst[i] = src[i];
    }
    __syncthreads();                                    // the only barrier

    const int tid = threadIdx.x;
    const int bid = blockIdx.x;
    const int st = bid & 15;                            // 16 strips of 32 cols
    const int rg = (bid >> 4) & 127;                    // 128 row groups of 4
    const int bb = bid >> 11;                           // batch
    const int wv = tid >> 6, lane = tid & 63;
    const int col = lane & 31, hi = lane >> 5;
    const int row = rg * 4 + wv;                        // each wave: one row x 32 px
    const int px0 = st * 32;

    // ---- perceive: lane (pixel=col, ch-block=hi) -> B1 frags af[5] in regs ----
    short8 af[5];
    {
        const bool rv0 = row > 0, rv2 = row < S - 1;
        const bool colInt = (px0 != 0) && (px0 != 480);
        const float* xb = x + (size_t)bb * S * S * CH;
        const int p = col;
#pragma unroll
        for (int qi = 0; qi < 2; ++qi) {
            const int q = hi * 2 + qi;                  // channel quad
            float4 A[3][3];
#pragma unroll
            for (int rr = 0; rr < 3; ++rr) {
                bool rok = (rr == 0) ? rv0 : (rr == 2 ? rv2 : true);
                if (rok) {
                    const float* rp = xb + (size_t)(row - 1 + rr) * S * CH + q * 4;
                    if (colInt) {
                        const float* bp = rp + (px0 + p - 1) * CH;
                        A[rr][0] = *reinterpret_cast<const float4*>(bp);
                        A[rr][1] = *reinterpret_cast<const float4*>(bp + CH);
                        A[rr][2] = *reinterpret_cast<const float4*>(bp + 2 * CH);
                    } else {
#pragma unroll
                        for (int d = 0; d < 3; ++d) {
                            int c = px0 + p - 1 + d;
                            int cl = min(max(c, 0), S - 1);
                            float4 v = *reinterpret_cast<const float4*>(rp + cl * CH);
                            if ((unsigned)c >= (unsigned)S) v = make_float4(0.f, 0.f, 0.f, 0.f);
                            A[rr][d] = v;
                        }
                    }
                } else {
                    A[rr][0] = make_float4(0.f, 0.f, 0.f, 0.f);
                    A[rr][1] = A[rr][0]; A[rr][2] = A[rr][0];
                }
            }
#pragma unroll
            for (int cc = 0; cc < 4; ++cc) {
                float a00 = ELT(A[0][0], cc), a01 = ELT(A[0][1], cc), a02 = ELT(A[0][2], cc);
                float a10 = ELT(A[1][0], cc), a11 = ELT(A[1][1], cc), a12 = ELT(A[1][2], cc);
                float a20 = ELT(A[2][0], cc), a21 = ELT(A[2][1], cc), a22 = ELT(A[2][2], cc);
                float cw0 = a00 + 2.f * a10 + a20;
                float cw1 = a01 + 2.f * a11 + a21;
                float cw2 = a02 + 2.f * a12 + a22;
                float rw0 = a00 + 2.f * a01 + a02;
                float rw2 = a20 + 2.f * a21 + a22;
                float fI  = a11;
                float fdx = (cw2 - cw0) * 0.125f;
                float fdy = (rw2 - rw0) * 0.125f;
                float flp = 0.25f * (cw0 + 2.f * cw1 + cw2) - 4.f * a11;
                float fav = ((cw0 + cw1 + cw2) - (a10 + a11 + a12)) * (1.f / 9.f);
                const int mb = (qi * 4 + cc) * 5;       // feature hi*40 + mb + f
                af[(mb + 0) >> 3][(mb + 0) & 7] = __builtin_bit_cast(short, (__bf16)fI);
                af[(mb + 1) >> 3][(mb + 1) & 7] = __builtin_bit_cast(short, (__bf16)fdx);
                af[(mb + 2) >> 3][(mb + 2) & 7] = __builtin_bit_cast(short, (__bf16)fdy);
                af[(mb + 3) >> 3][(mb + 3) & 7] = __builtin_bit_cast(short, (__bf16)flp);
                af[(mb + 4) >> 3][(mb + 4) & 7] = __builtin_bit_cast(short, (__bf16)fav);
            }
        }
    }

    const short8* wf = reinterpret_cast<const short8*>(wlds);

    // ---- GEMM1: h1[64f x 32px] = W1^T * Y ----
    f32x16 acc1[2];
#pragma unroll
    for (int n = 0; n < 2; ++n) {
        f32x16 acc = {};
#pragma unroll
        for (int s = 0; s < 5; ++s) {
            bf16x8 a = __builtin_bit_cast(bf16x8, wf[(n * 5 + s) * 64 + lane]);
            bf16x8 b = __builtin_bit_cast(bf16x8, af[s]);
            acc = __builtin_amdgcn_mfma_f32_32x32x16_bf16(a, b, acc, 0, 0, 0);
        }
        acc1[n] = acc;
    }

    // ---- swish + bias -> B2 frags (pure registers; reg (t&1)*8+j holds k-slot j) ----
    short8 b2f[4];
#pragma unroll
    for (int t = 0; t < 4; ++t) {
        int n = t >> 1;
        float4 bq0 = *reinterpret_cast<const float4*>(wsb + n * 32 + 4 * hi + 16 * (t & 1));
        float4 bq1 = *reinterpret_cast<const float4*>(wsb + n * 32 + 4 * hi + 16 * (t & 1) + 8);
#pragma unroll
        for (int j = 0; j < 8; ++j) {
            float bias = (j < 4) ? ELT(bq0, j & 3) : ELT(bq1, j & 3);
            float h = swishf(acc1[n][(t & 1) * 8 + j] + bias);
            b2f[t][j] = __builtin_bit_cast(short, (__bf16)h);
        }
    }

    // ---- GEMM2: h2[32f x 32px] = W2^T * h1 ----
    f32x16 acc2 = {};
#pragma unroll
    for (int t = 0; t < 4; ++t) {
        bf16x8 a = __builtin_bit_cast(bf16x8, wf[(10 + t) * 64 + lane]);
        acc2 = __builtin_amdgcn_mfma_f32_32x32x16_bf16(a, __builtin_bit_cast(bf16x8, b2f[t]), acc2, 0, 0, 0);
    }

    short8 b3f[2];
#pragma unroll
    for (int t = 0; t < 2; ++t) {
        float4 cq0 = *reinterpret_cast<const float4*>(wsb + 64 + 4 * hi + 16 * t);
        float4 cq1 = *reinterpret_cast<const float4*>(wsb + 64 + 4 * hi + 16 * t + 8);
#pragma unroll
        for (int j = 0; j < 8; ++j) {
            float bias = (j < 4) ? ELT(cq0, j & 3) : ELT(cq1, j & 3);
            float h = swishf(acc2[t * 8 + j] + bias);
            b3f[t][j] = __builtin_bit_cast(short, (__bf16)h);
        }
    }

    // ---- GEMM3: dx[16f x 32px] = W3^T(pad32) * h2 ----
    f32x16 acc3 = {};
#pragma unroll
    for (int t = 0; t < 2; ++t) {
        bf16x8 a = __builtin_bit_cast(bf16x8, wf[(14 + t) * 64 + lane]);
        acc3 = __builtin_amdgcn_mfma_f32_32x32x16_bf16(a, __builtin_bit_cast(bf16x8, b3f[t]), acc3, 0, 0, 0);
    }

    // ---- epilogue: regs r=0..7 -> ch = 4*hi + (r&3) + 8*(r>>2); coalesced float4 x2 ----
    size_t pix = ((size_t)(bb * S + row)) * S + px0 + col;
    float msk = (noise[pix] <= 0.5f) ? 1.f : 0.f;
    float4 bA = *reinterpret_cast<const float4*>(wsb + 96 + 4 * hi);
    float4 bB = *reinterpret_cast<const float4*>(wsb + 96 + 8 + 4 * hi);
    const float* xp = x + pix * CH;
    float4 c0 = *reinterpret_cast<const float4*>(xp + 4 * hi);
    float4 c1 = *reinterpret_cast<const float4*>(xp + 8 + 4 * hi);
    float4 o0, o1;
    o0.x = c0.x + (acc3[0] + bA.x) * msk;
    o0.y = c0.y + (acc3[1] + bA.y) * msk;
    o0.z = c0.z + (acc3[2] + bA.z) * msk;
    o0.w = c0.w + (acc3[3] + bA.w) * msk;
    o1.x = c1.x + (acc3[4] + bB.x) * msk;
    o1.y = c1.y + (acc3[5] + bB.y) * msk;
    o1.z = c1.z + (acc3[6] + bB.z) * msk;
    o1.w = c1.w + (acc3[7] + bB.w) * msk;
    *reinterpret_cast<float4*>(out + pix * CH + 4 * hi) = o0;
    *reinterpret_cast<float4*>(out + pix * CH + 8 + 4 * hi) = o1;
}

extern "C" void kernel_launch(void* const* d_in, const int* in_sizes, int n_in,
                              void* d_out, int out_size, void* d_ws, size_t ws_size,
                              hipStream_t stream)
{
    const float* x     = (const float*)d_in[0];
    const float* noise = (const float*)d_in[1];
    const float* W1    = (const float*)d_in[2];
    const float* b1    = (const float*)d_in[3];
    const float* W2    = (const float*)d_in[4];
    const float* b2    = (const float*)d_in[5];
    const float* W3    = (const float*)d_in[6];
    const float* b3    = (const float*)d_in[7];
    short* wsf = (short*)d_ws;
    float* wsb = (float*)((char*)d_ws + 16384);
    float* out = (float*)d_out;

    hipLaunchKernelGGL(prep_weights, dim3(32), dim3(256), 0, stream,
                       W1, b1, W2, b2, W3, b3, wsf, wsb);
    hipLaunchKernelGGL(nca_fused, dim3(4 * 128 * 16), dim3(256), 0, stream,
                       x, noise, wsf, wsb, out);
}